// Round 6
// baseline (1272.821 us; speedup 1.0000x reference)
//
#include <hip/hip_runtime.h>
#include <hip/hip_bf16.h>
#include <math.h>

typedef __bf16 bf16;
typedef __bf16 bf16x8 __attribute__((ext_vector_type(8)));
typedef float  f32x4  __attribute__((ext_vector_type(4)));

#define B_   8
#define T_   1024
#define H_   1024
#define MTOK (B_ * T_)   // 8192 token rows

static __device__ __forceinline__ float gelu_f(float x) {
    return 0.5f * x * (1.0f + erff(x * 0.70710678118654752f));
}

// async global->LDS, 16B per lane. LDS dest = wave-uniform base + lane*16.
static __device__ __forceinline__ void async16(const bf16* g, bf16* l) {
    __builtin_amdgcn_global_load_lds(
        (const __attribute__((address_space(1))) void*)g,
        (__attribute__((address_space(3))) void*)l, 16, 0, 0);
}

// ---------------------------------------------------------------------------
// Weight prep: fp32 (K x N) -> bf16 (N x K)  (transpose + cast)
// ---------------------------------------------------------------------------
__global__ __launch_bounds__(256)
void transpose_cast_k(const float* __restrict__ in, bf16* __restrict__ out,
                      int Kd, int Nd)
{
    __shared__ float tile[32][33];
    int n0 = blockIdx.x * 32;
    int k0 = blockIdx.y * 32;
    int tx = threadIdx.x & 31, ty = threadIdx.x >> 5;   // 32 x 8
#pragma unroll
    for (int i = 0; i < 32; i += 8)
        tile[ty + i][tx] = in[(size_t)(k0 + ty + i) * Nd + n0 + tx];
    __syncthreads();
#pragma unroll
    for (int i = 0; i < 32; i += 8)
        out[(size_t)(n0 + ty + i) * Kd + k0 + tx] = (bf16)tile[tx][ty + i];
}

// fp32 -> bf16 elementwise (pw_w is already [o][c] = [n][k])
__global__ __launch_bounds__(256)
void cast_k(const float* __restrict__ in, bf16* __restrict__ out)
{
    int i = blockIdx.x * 256 + threadIdx.x;
    float4 v = ((const float4*)in)[i];
    bf16* o = out + (size_t)i * 4;
    o[0] = (bf16)v.x; o[1] = (bf16)v.y; o[2] = (bf16)v.z; o[3] = (bf16)v.w;
}

// ---------------------------------------------------------------------------
// V transpose: qkv[b*T+t][2048 + h*64 + hd] -> vt[(bh*64 + hd)*T + t]
// ---------------------------------------------------------------------------
__global__ __launch_bounds__(256)
void transpose_v_k(const bf16* __restrict__ qkv, bf16* __restrict__ vt)
{
    __shared__ bf16 tile[64][72];
    const int t0 = blockIdx.x * 64;
    const int bh = blockIdx.y;
    const int b = bh >> 4, h = bh & 15;
    const int tid = threadIdx.x;
#pragma unroll
    for (int i = 0; i < 2; i++) {
        int c = tid + i * 256;
        int row = c >> 3, ch = (c & 7) << 3;
        *(bf16x8*)(&tile[row][ch]) =
            *(const bf16x8*)(&qkv[(size_t)(b * T_ + t0 + row) * 3072 + 2048 + h * 64 + ch]);
    }
    __syncthreads();
#pragma unroll
    for (int i = 0; i < 2; i++) {
        int c = tid + i * 256;
        int hd = c >> 3, tc = (c & 7) << 3;
        bf16x8 v;
#pragma unroll
        for (int j = 0; j < 8; j++) v[j] = tile[tc + j][hd];
        *(bf16x8*)(&vt[((size_t)bh * 64 + hd) * T_ + t0 + tc]) = v;
    }
}

// ---------------------------------------------------------------------------
// LayerNorm over H=1024, fp32 in -> bf16 out. One block per row.
// ---------------------------------------------------------------------------
__global__ __launch_bounds__(256)
void ln_k(const float* __restrict__ x, const float* __restrict__ g,
          const float* __restrict__ b, bf16* __restrict__ out)
{
    int row = blockIdx.x;
    float4 v = ((const float4*)(x + (size_t)row * H_))[threadIdx.x];
    float s  = v.x + v.y + v.z + v.w;
    float s2 = v.x * v.x + v.y * v.y + v.z * v.z + v.w * v.w;
#pragma unroll
    for (int off = 32; off > 0; off >>= 1) {
        s  += __shfl_down(s, off);
        s2 += __shfl_down(s2, off);
    }
    __shared__ float red[8];
    int wave = threadIdx.x >> 6, lane = threadIdx.x & 63;
    if (lane == 0) { red[wave] = s; red[wave + 4] = s2; }
    __syncthreads();
    s  = red[0] + red[1] + red[2] + red[3];
    s2 = red[4] + red[5] + red[6] + red[7];
    float mean = s * (1.0f / H_);
    float var  = s2 * (1.0f / H_) - mean * mean;
    float rstd = rsqrtf(var + 1e-5f);
    int c = threadIdx.x * 4;
    float4 gv = *(const float4*)(g + c);
    float4 bv = *(const float4*)(b + c);
    bf16* o = out + (size_t)row * H_ + c;
    o[0] = (bf16)((v.x - mean) * rstd * gv.x + bv.x);
    o[1] = (bf16)((v.y - mean) * rstd * gv.y + bv.y);
    o[2] = (bf16)((v.z - mean) * rstd * gv.z + bv.z);
    o[3] = (bf16)((v.w - mean) * rstd * gv.w + bv.w);
}

// ---------------------------------------------------------------------------
// Causal depthwise conv (k=3) + bias + exact GELU. Token-major, bf16->bf16.
// ---------------------------------------------------------------------------
__global__ __launch_bounds__(256)
void dwconv_k(const bf16* __restrict__ cl, const float* __restrict__ kw,
              const float* __restrict__ kb, bf16* __restrict__ out)
{
    size_t idx = (size_t)blockIdx.x * 256 + threadIdx.x;
    int ch = (int)(idx & (H_ - 1));
    int t  = (int)((idx >> 10) & (T_ - 1));
    float acc = kb[ch];
    float w0 = kw[ch * 3 + 0], w1 = kw[ch * 3 + 1], w2 = kw[ch * 3 + 2];
    acc += (float)cl[idx] * w2;
    if (t >= 1) acc += (float)cl[idx - H_] * w1;
    if (t >= 2) acc += (float)cl[idx - 2 * H_] * w0;
    out[idx] = (bf16)gelu_f(acc);
}

// ---------------------------------------------------------------------------
// LDS-free register-pipelined bf16 GEMM, BM=BN=128 (per-wave 64x64).
// No barriers in the K-loop: fragments load straight from global (A row-major
// [m][k], WT [n][k] are already MFMA-fragment-shaped; each load = 16 rows x
// 64B segments, L1/L2-served). 1-step lookahead; compiler emits vmcnt(N)
// waits one full MFMA stage after issue.
// EPI: 0 = gelu(acc+bias)->bf16, 1 = (acc+bias)->bf16,
//      2 = acc+bias+res -> fp32 (res may alias out), 3 = res + 0.5*(acc+bias) -> fp32
// ---------------------------------------------------------------------------
template<int EPI>
__global__ __launch_bounds__(256)
void gemm_r(const bf16* __restrict__ A, const bf16* __restrict__ WT,
            const float* __restrict__ bias, const float* __restrict__ res,
            float* __restrict__ outF, bf16* __restrict__ outB,
            int N, int K)
{
    const int tid  = threadIdx.x;
    const int wave = tid >> 6;
    const int lane = tid & 63;
    const int quad = lane >> 4;
    const int lr   = lane & 15;
    const int bm = blockIdx.x * 128;
    const int bn = blockIdx.y * 128;
    const int wm = (wave & 1) * 64;
    const int wn = (wave >> 1) * 64;

    const bf16* pA = A  + (size_t)(bm + wm + lr) * K + quad * 8;
    const bf16* pB = WT + (size_t)(bn + wn + lr) * K + quad * 8;
    const size_t rs = (size_t)16 * K;     // 16-row stride

    f32x4 acc[4][4];
#pragma unroll
    for (int mi = 0; mi < 4; mi++)
#pragma unroll
        for (int ni = 0; ni < 4; ni++)
#pragma unroll
            for (int r = 0; r < 4; r++) acc[mi][ni][r] = 0.f;

    bf16x8 a0[4], b0[4], a1[4], b1[4];

    auto ld = [&](int k, bf16x8 (&af)[4], bf16x8 (&bf)[4]) {
#pragma unroll
        for (int i = 0; i < 4; i++) {
            af[i] = *(const bf16x8*)(pA + i * rs + k);
            bf[i] = *(const bf16x8*)(pB + i * rs + k);
        }
    };
    auto comp = [&](bf16x8 (&af)[4], bf16x8 (&bf)[4]) {
#pragma unroll
        for (int mi = 0; mi < 4; mi++)
#pragma unroll
            for (int ni = 0; ni < 4; ni++)
                acc[mi][ni] = __builtin_amdgcn_mfma_f32_16x16x32_bf16(
                    af[mi], bf[ni], acc[mi][ni], 0, 0, 0);
    };

    ld(0, a0, b0);
    for (int k = 0; k < K; k += 64) {      // K is a multiple of 64
        ld(k + 32, a1, b1);
        comp(a0, b0);
        if (k + 64 < K) ld(k + 64, a0, b0);
        comp(a1, b1);
    }

    // epilogue — C/D layout: col = lane&15, row = quad*4 + reg  [m89-verified]
#pragma unroll
    for (int mi = 0; mi < 4; mi++) {
#pragma unroll
        for (int ni = 0; ni < 4; ni++) {
            int col = bn + wn + ni * 16 + lr;
            float bv = bias[col];
#pragma unroll
            for (int r = 0; r < 4; r++) {
                int row = bm + wm + mi * 16 + quad * 4 + r;
                size_t idx = (size_t)row * N + col;
                float v = acc[mi][ni][r] + bv;
                if (EPI == 0)      outB[idx] = (bf16)gelu_f(v);
                else if (EPI == 1) outB[idx] = (bf16)v;
                else if (EPI == 2) outF[idx] = v + res[idx];
                else               outF[idx] = res[idx] + 0.5f * v;
            }
        }
    }
}

// ---------------------------------------------------------------------------
// LDS-free register-pipelined GEMM, BM=64 BN=128 (per-wave 32x64), for
// N=1024 shapes (grid 128x8 = 1024 blocks = 4/CU). 2-step lookahead with
// 4 rotating buffers (8 MFMA per step is a thinner latency cover).
// ---------------------------------------------------------------------------
template<int EPI>
__global__ __launch_bounds__(256)
void gemm64_r(const bf16* __restrict__ A, const bf16* __restrict__ WT,
              const float* __restrict__ bias, const float* __restrict__ res,
              float* __restrict__ outF, bf16* __restrict__ outB,
              int N, int K)
{
    const int tid  = threadIdx.x;
    const int wave = tid >> 6;
    const int lane = tid & 63;
    const int quad = lane >> 4;
    const int lr   = lane & 15;
    const int bm = blockIdx.x * 64;
    const int bn = blockIdx.y * 128;
    const int wm = (wave & 1) * 32;
    const int wn = (wave >> 1) * 64;

    const bf16* pA = A  + (size_t)(bm + wm + lr) * K + quad * 8;
    const bf16* pB = WT + (size_t)(bn + wn + lr) * K + quad * 8;
    const size_t rs = (size_t)16 * K;

    f32x4 acc[2][4];
#pragma unroll
    for (int mi = 0; mi < 2; mi++)
#pragma unroll
        for (int ni = 0; ni < 4; ni++)
#pragma unroll
            for (int r = 0; r < 4; r++) acc[mi][ni][r] = 0.f;

    bf16x8 a[4][2], b[4][4];   // 4 rotating k-step buffers

    auto ld = [&](int k, int s) {
        if (k < K) {
#pragma unroll
            for (int i = 0; i < 2; i++) a[s][i] = *(const bf16x8*)(pA + i * rs + k);
#pragma unroll
            for (int i = 0; i < 4; i++) b[s][i] = *(const bf16x8*)(pB + i * rs + k);
        }
    };
    auto comp = [&](int s) {
#pragma unroll
        for (int mi = 0; mi < 2; mi++)
#pragma unroll
            for (int ni = 0; ni < 4; ni++)
                acc[mi][ni] = __builtin_amdgcn_mfma_f32_16x16x32_bf16(
                    a[s][mi], b[s][ni], acc[mi][ni], 0, 0, 0);
    };

    ld(0, 0);
    ld(32, 1);
    for (int k = 0; k < K; k += 128) {     // K is a multiple of 128 here
        ld(k + 64, 2);  comp(0);
        ld(k + 96, 3);  comp(1);
        ld(k + 128, 0); comp(2);
        ld(k + 160, 1); comp(3);
    }

#pragma unroll
    for (int mi = 0; mi < 2; mi++) {
#pragma unroll
        for (int ni = 0; ni < 4; ni++) {
            int col = bn + wn + ni * 16 + lr;
            float bv = bias[col];
#pragma unroll
            for (int r = 0; r < 4; r++) {
                int row = bm + wm + mi * 16 + quad * 4 + r;
                size_t idx = (size_t)row * N + col;
                float v = acc[mi][ni][r] + bv;
                if (EPI == 0)      outB[idx] = (bf16)gelu_f(v);
                else if (EPI == 1) outB[idx] = (bf16)v;
                else if (EPI == 2) outF[idx] = v + res[idx];
                else               outF[idx] = res[idx] + 0.5f * v;
            }
        }
    }
}

// ---------------------------------------------------------------------------
// Flash attention (R4 version): grid (8 q-blocks of 128 rows, B*NH). 4 waves;
// wave owns two 16-row q stripes. Cooperative K/V staging via global_load_lds.
// No-max softmax (|s| bounded), deferred l-reduction.
// qkv: row-major [b*T+t][3072], k at +1024. vt: [bh*64+hd][t].
// ---------------------------------------------------------------------------
__global__ __launch_bounds__(256)
void attn_k(const bf16* __restrict__ qkv, const bf16* __restrict__ vt,
            bf16* __restrict__ o)
{
    const int B0 = blockIdx.x;          // 0..7  (128 q rows each)
    const int bh = blockIdx.y;          // b*16 + h
    const int b = bh >> 4, h = bh & 15;
    const int tid  = threadIdx.x;
    const int wave = tid >> 6, lane = tid & 63;
    const int quad = lane >> 4, lr = lane & 15;

    __shared__ __align__(16) bf16 Ks[2][64 * 32];   // [half][s-row][32 hd]
    __shared__ __align__(16) bf16 Vs[2][64 * 32];   // [half][hd-row][32 s]
    __shared__ __align__(16) bf16 Ps[4][16 * 72];   // per-wave P stripe [q][s]

    const int crow = lane >> 2;          // 0..15
    const int ccol = (lane & 3) << 3;    // 0,8,16,24

    const int qa = B0 * 128 + wave * 16;         // stripe a base q row
    const int qb = qa + 64;                      // stripe b base q row

    // Q fragments direct from global; fold softmax scale 1/8 (exact in bf16)
    bf16x8 qfa[2], qfb[2];
    {
        const size_t ra = ((size_t)(b * T_ + qa + lr)) * 3072 + h * 64;
        const size_t rb = ((size_t)(b * T_ + qb + lr)) * 3072 + h * 64;
        qfa[0] = *(const bf16x8*)(&qkv[ra + quad * 8]);
        qfa[1] = *(const bf16x8*)(&qkv[ra + 32 + quad * 8]);
        qfb[0] = *(const bf16x8*)(&qkv[rb + quad * 8]);
        qfb[1] = *(const bf16x8*)(&qkv[rb + 32 + quad * 8]);
#pragma unroll
        for (int j = 0; j < 8; j++) {
            qfa[0][j] = (bf16)((float)qfa[0][j] * 0.125f);
            qfa[1][j] = (bf16)((float)qfa[1][j] * 0.125f);
            qfb[0][j] = (bf16)((float)qfb[0][j] * 0.125f);
            qfb[1][j] = (bf16)((float)qfb[1][j] * 0.125f);
        }
    }

    f32x4 oa[4], ob[4];
    float la[4], lb[4];
#pragma unroll
    for (int ni = 0; ni < 4; ni++)
#pragma unroll
        for (int r = 0; r < 4; r++) { oa[ni][r] = 0.f; ob[ni][r] = 0.f; }
#pragma unroll
    for (int r = 0; r < 4; r++) { la[r] = 0.f; lb[r] = 0.f; }

    const size_t kbase = (size_t)b * T_ * 3072 + 1024 + h * 64;
    const size_t vbase = (size_t)bh * 64 * T_;

    auto stripe = [&](const bf16x8 (&qf)[2], f32x4 (&oacc)[4], float (&lsum)[4],
                      int q0, int kcol0, bool diag) {
        bf16x8 kf0[4], kf1[4];
#pragma unroll
        for (int ni = 0; ni < 4; ni++) {
            kf0[ni] = *(const bf16x8*)(&Ks[0][(ni * 16 + lr) * 32 + quad * 8]);
            kf1[ni] = *(const bf16x8*)(&Ks[1][(ni * 16 + lr) * 32 + quad * 8]);
        }
        f32x4 sv[4];
#pragma unroll
        for (int ni = 0; ni < 4; ni++) {
            f32x4 t;
#pragma unroll
            for (int r = 0; r < 4; r++) t[r] = 0.f;
            t = __builtin_amdgcn_mfma_f32_16x16x32_bf16(qf[0], kf0[ni], t, 0, 0, 0);
            t = __builtin_amdgcn_mfma_f32_16x16x32_bf16(qf[1], kf1[ni], t, 0, 0, 0);
            sv[ni] = t;
        }
        if (diag) {
#pragma unroll
            for (int ni = 0; ni < 4; ni++)
#pragma unroll
                for (int r = 0; r < 4; r++)
                    if (kcol0 + ni * 16 + lr > q0 + quad * 4 + r)
                        sv[ni][r] = -INFINITY;
        }
#pragma unroll
        for (int ni = 0; ni < 4; ni++)
#pragma unroll
            for (int r = 0; r < 4; r++) {
                float p = __expf(sv[ni][r]);   // no-max softmax: |s| bounded
                lsum[r] += p;
                Ps[wave][(quad * 4 + r) * 72 + ni * 16 + lr] = (bf16)p;
            }
        bf16x8 pf0 = *(const bf16x8*)(&Ps[wave][lr * 72 + quad * 8]);
        bf16x8 pf1 = *(const bf16x8*)(&Ps[wave][lr * 72 + 32 + quad * 8]);
#pragma unroll
        for (int ni = 0; ni < 4; ni++) {
            bf16x8 vf0 = *(const bf16x8*)(&Vs[0][(ni * 16 + lr) * 32 + quad * 8]);
            bf16x8 vf1 = *(const bf16x8*)(&Vs[1][(ni * 16 + lr) * 32 + quad * 8]);
            oacc[ni] = __builtin_amdgcn_mfma_f32_16x16x32_bf16(pf0, vf0, oacc[ni], 0, 0, 0);
            oacc[ni] = __builtin_amdgcn_mfma_f32_16x16x32_bf16(pf1, vf1, oacc[ni], 0, 0, 0);
        }
    };

    const int ktmax = 2 * B0 + 1;
    for (int kt = 0; kt <= ktmax; kt++) {
        __syncthreads();
#pragma unroll
        for (int half = 0; half < 2; half++) {
            async16(&qkv[kbase + (size_t)(kt * 64 + wave * 16 + crow) * 3072 + half * 32 + ccol],
                    &Ks[half][wave * 512]);
            async16(&vt[vbase + (size_t)(wave * 16 + crow) * T_ + kt * 64 + half * 32 + ccol],
                    &Vs[half][wave * 512]);
        }
        __syncthreads();
        if (kt <= 2 * B0)
            stripe(qfa, oa, la, qa, kt * 64, kt == 2 * B0);
        stripe(qfb, ob, lb, qb, kt * 64, kt == ktmax);
    }

    // final l reduction across the 16 lanes of each row group
#pragma unroll
    for (int off = 1; off < 16; off <<= 1)
#pragma unroll
        for (int r = 0; r < 4; r++) {
            la[r] += __shfl_xor(la[r], off);
            lb[r] += __shfl_xor(lb[r], off);
        }

#pragma unroll
    for (int r = 0; r < 4; r++) {
        float inva = 1.0f / la[r], invb = 1.0f / lb[r];
        int ga = qa + quad * 4 + r, gb = qb + quad * 4 + r;
#pragma unroll
        for (int ni = 0; ni < 4; ni++) {
            o[((size_t)(b * T_ + ga)) * H_ + h * 64 + ni * 16 + lr] = (bf16)(oa[ni][r] * inva);
            o[((size_t)(b * T_ + gb)) * H_ + h * 64 + ni * 16 + lr] = (bf16)(ob[ni][r] * invb);
        }
    }
}

// ---------------------------------------------------------------------------
extern "C" void kernel_launch(void* const* d_in, const int* in_sizes, int n_in,
                              void* d_out, int out_size, void* d_ws, size_t ws_size,
                              hipStream_t stream)
{
    const float* x_in  = (const float*)d_in[0];
    const float* ln1_g = (const float*)d_in[1];
    const float* ln1_b = (const float*)d_in[2];
    const float* f1w1  = (const float*)d_in[3];
    const float* f1b1  = (const float*)d_in[4];
    const float* f1w2  = (const float*)d_in[5];
    const float* f1b2  = (const float*)d_in[6];
    const float* an_g  = (const float*)d_in[7];
    const float* an_b  = (const float*)d_in[8];
    const float* qkv_w = (const float*)d_in[9];
    const float* qkv_b = (const float*)d_in[10];
    const float* out_w = (const float*)d_in[11];
    const float* out_b = (const float*)d_in[12];
    const float* cn_g  = (const float*)d_in[13];
    const float* cn_b  = (const float*)d_in[14];
    const float* dw_k  = (const float*)d_in[15];
    const float* dw_b  = (const float*)d_in[16];
    const float* pw_w  = (const float*)d_in[17];
    const float* pw_b  = (const float*)d_in[18];
    const float* ln2_g = (const float*)d_in[19];
    const float* ln2_b = (const float*)d_in[20];
    const float* f2w1  = (const float*)d_in[21];
    const float* f2b1  = (const float*)d_in[22];
    const float* f2w2  = (const float*)d_in[23];
    const float* f2b2  = (const float*)d_in[24];
    float* outp = (float*)d_out;

    char* ws = (char*)d_ws;
    size_t off = 0;
    auto alloc = [&](size_t bytes) {
        char* p = ws + off;
        off += (bytes + 255) & ~(size_t)255;
        return p;
    };
    bf16* w1T_1 = (bf16*)alloc(2048ULL * 1024 * 2);
    bf16* w2T_1 = (bf16*)alloc(1024ULL * 2048 * 2);
    bf16* qkvT  = (bf16*)alloc(3072ULL * 1024 * 2);
    bf16* outT  = (bf16*)alloc(1024ULL * 1024 * 2);
    bf16* pwB   = (bf16*)alloc(1024ULL * 1024 * 2);
    bf16* w1T_2 = (bf16*)alloc(2048ULL * 1024 * 2);
    bf16* w2T_2 = (bf16*)alloc(1024ULL * 2048 * 2);
    bf16* bufa  = (bf16*)alloc((size_t)MTOK * 1024 * 2);   // LN outs / attn out
    bf16* gbuf  = (bf16*)alloc((size_t)MTOK * 1024 * 2);   // conv-gelu out / vt alias
    bf16* hid   = (bf16*)alloc((size_t)MTOK * 3072 * 2);   // ffn hidden / qkv
    float* xw   = (float*)alloc((size_t)MTOK * 1024 * 4);  // running residual x
    bf16* vt    = gbuf;   // time-disjoint alias: vt live only during attention

    // ---- weight prep (bf16, B pre-transposed to [n][k]) ----
    transpose_cast_k<<<dim3(64, 32), 256, 0, stream>>>(f1w1, w1T_1, 1024, 2048);
    transpose_cast_k<<<dim3(32, 64), 256, 0, stream>>>(f1w2, w2T_1, 2048, 1024);
    transpose_cast_k<<<dim3(96, 32), 256, 0, stream>>>(qkv_w, qkvT, 1024, 3072);
    transpose_cast_k<<<dim3(32, 32), 256, 0, stream>>>(out_w, outT, 1024, 1024);
    transpose_cast_k<<<dim3(64, 32), 256, 0, stream>>>(f2w1, w1T_2, 1024, 2048);
    transpose_cast_k<<<dim3(32, 64), 256, 0, stream>>>(f2w2, w2T_2, 2048, 1024);
    cast_k<<<1024, 256, 0, stream>>>(pw_w, pwB);

    // ---- FFN1 (x += 0.5 * ffn(ln1(x))) ----
    ln_k<<<MTOK, 256, 0, stream>>>(x_in, ln1_g, ln1_b, bufa);
    gemm_r<0><<<dim3(64, 16), 256, 0, stream>>>(bufa, w1T_1, f1b1, nullptr, nullptr, hid, 2048, 1024);
    gemm64_r<3><<<dim3(128, 8), 256, 0, stream>>>(hid, w2T_1, f1b2, x_in, xw, nullptr, 1024, 2048);

    // ---- attention ----
    ln_k<<<MTOK, 256, 0, stream>>>(xw, an_g, an_b, bufa);
    gemm_r<1><<<dim3(64, 24), 256, 0, stream>>>(bufa, qkvT, qkv_b, nullptr, nullptr, hid, 3072, 1024);
    transpose_v_k<<<dim3(16, 128), 256, 0, stream>>>(hid, vt);
    attn_k<<<dim3(8, 128), 256, 0, stream>>>(hid, vt, bufa);
    gemm64_r<2><<<dim3(128, 8), 256, 0, stream>>>(bufa, outT, out_b, xw, xw, nullptr, 1024, 1024);

    // ---- conv module ----
    ln_k<<<MTOK, 256, 0, stream>>>(xw, cn_g, cn_b, bufa);
    dwconv_k<<<MTOK * 1024 / 256, 256, 0, stream>>>(bufa, dw_k, dw_b, gbuf);
    gemm64_r<2><<<dim3(128, 8), 256, 0, stream>>>(gbuf, pwB, pw_b, xw, xw, nullptr, 1024, 1024);

    // ---- FFN2 ----
    ln_k<<<MTOK, 256, 0, stream>>>(xw, ln2_g, ln2_b, bufa);
    gemm_r<0><<<dim3(64, 16), 256, 0, stream>>>(bufa, w1T_2, f2b1, nullptr, nullptr, hid, 2048, 1024);
    gemm64_r<3><<<dim3(128, 8), 256, 0, stream>>>(hid, w2T_2, f2b2, xw, outp, nullptr, 1024, 2048);
}

// Round 7
// 666.600 us; speedup vs baseline: 1.9094x; 1.9094x over previous
//
#include <hip/hip_runtime.h>
#include <hip/hip_bf16.h>
#include <math.h>

typedef __bf16 bf16;
typedef __bf16 bf16x4 __attribute__((ext_vector_type(4)));
typedef __bf16 bf16x8 __attribute__((ext_vector_type(8)));
typedef float  f32x4  __attribute__((ext_vector_type(4)));

#define B_   8
#define T_   1024
#define H_   1024
#define MTOK (B_ * T_)   // 8192 token rows

static __device__ __forceinline__ float gelu_f(float x) {
    return 0.5f * x * (1.0f + erff(x * 0.70710678118654752f));
}

// async global->LDS, 16B per lane. LDS dest = wave-uniform base + lane*16.
static __device__ __forceinline__ void async16(const bf16* g, bf16* l) {
    __builtin_amdgcn_global_load_lds(
        (const __attribute__((address_space(1))) void*)g,
        (__attribute__((address_space(3))) void*)l, 16, 0, 0);
}

// ---------------------------------------------------------------------------
// Consolidated weight prep (one launch). mode 0: fp32 [Kd][Nd] -> bf16
// [Nd][Kd] (transpose+cast, 32x32 LDS tiles); mode 1: plain cast (1024
// elems/block).
// ---------------------------------------------------------------------------
struct PrepTab {
    const float* in[7];
    bf16*        out[7];
    int kd[7], nd[7], mode[7];
    int bx0[8];          // cumulative block offsets
};

__global__ __launch_bounds__(256)
void prep_k(PrepTab tab)
{
    __shared__ float tile[32][33];
    int bx = blockIdx.x;
    int j = 0;
    while (bx >= tab.bx0[j + 1]) j++;
    int local = bx - tab.bx0[j];
    const float* in = tab.in[j];
    bf16* out = tab.out[j];
    if (tab.mode[j] == 0) {
        int Kd = tab.kd[j], Nd = tab.nd[j];
        int nbn = Nd >> 5;
        int n0 = (local % nbn) * 32;
        int k0 = (local / nbn) * 32;
        int tx = threadIdx.x & 31, ty = threadIdx.x >> 5;   // 32 x 8
#pragma unroll
        for (int i = 0; i < 32; i += 8)
            tile[ty + i][tx] = in[(size_t)(k0 + ty + i) * Nd + n0 + tx];
        __syncthreads();
#pragma unroll
        for (int i = 0; i < 32; i += 8)
            out[(size_t)(n0 + ty + i) * Kd + k0 + tx] = (bf16)tile[tx][ty + i];
    } else {
        size_t i = (size_t)local * 1024 + threadIdx.x * 4;
        float4 v = *(const float4*)(in + i);
        bf16* o = out + i;
        o[0] = (bf16)v.x; o[1] = (bf16)v.y; o[2] = (bf16)v.z; o[3] = (bf16)v.w;
    }
}

// ---------------------------------------------------------------------------
// LayerNorm over H=1024, fp32 in -> bf16 out. One block per row.
// ---------------------------------------------------------------------------
__global__ __launch_bounds__(256)
void ln_k(const float* __restrict__ x, const float* __restrict__ g,
          const float* __restrict__ b, bf16* __restrict__ out)
{
    int row = blockIdx.x;
    float4 v = ((const float4*)(x + (size_t)row * H_))[threadIdx.x];
    float s  = v.x + v.y + v.z + v.w;
    float s2 = v.x * v.x + v.y * v.y + v.z * v.z + v.w * v.w;
#pragma unroll
    for (int off = 32; off > 0; off >>= 1) {
        s  += __shfl_down(s, off);
        s2 += __shfl_down(s2, off);
    }
    __shared__ float red[8];
    int wave = threadIdx.x >> 6, lane = threadIdx.x & 63;
    if (lane == 0) { red[wave] = s; red[wave + 4] = s2; }
    __syncthreads();
    s  = red[0] + red[1] + red[2] + red[3];
    s2 = red[4] + red[5] + red[6] + red[7];
    float mean = s * (1.0f / H_);
    float var  = s2 * (1.0f / H_) - mean * mean;
    float rstd = rsqrtf(var + 1e-5f);
    int c = threadIdx.x * 4;
    float4 gv = *(const float4*)(g + c);
    float4 bv = *(const float4*)(b + c);
    bf16* o = out + (size_t)row * H_ + c;
    o[0] = (bf16)((v.x - mean) * rstd * gv.x + bv.x);
    o[1] = (bf16)((v.y - mean) * rstd * gv.y + bv.y);
    o[2] = (bf16)((v.z - mean) * rstd * gv.z + bv.z);
    o[3] = (bf16)((v.w - mean) * rstd * gv.w + bv.w);
}

// ---------------------------------------------------------------------------
// Causal depthwise conv (k=3) + bias + exact GELU. Token-major, bf16->bf16.
// ---------------------------------------------------------------------------
__global__ __launch_bounds__(256)
void dwconv_k(const bf16* __restrict__ cl, const float* __restrict__ kw,
              const float* __restrict__ kb, bf16* __restrict__ out)
{
    size_t idx = (size_t)blockIdx.x * 256 + threadIdx.x;
    int ch = (int)(idx & (H_ - 1));
    int t  = (int)((idx >> 10) & (T_ - 1));
    float acc = kb[ch];
    float w0 = kw[ch * 3 + 0], w1 = kw[ch * 3 + 1], w2 = kw[ch * 3 + 2];
    acc += (float)cl[idx] * w2;
    if (t >= 1) acc += (float)cl[idx - H_] * w1;
    if (t >= 2) acc += (float)cl[idx - 2 * H_] * w0;
    out[idx] = (bf16)gelu_f(acc);
}

// ---------------------------------------------------------------------------
// bf16 MFMA GEMM (BM=128): C = A(MxK) @ WT(NxK)^T. BK=32, double-buffered
// LDS, prefetch issued before compute, one barrier per k-step.
// EPI: 0 = gelu(acc+bias)->bf16, 1 = (acc+bias)->bf16,
//      2 = acc+bias+res -> fp32 (res may alias out), 3 = res + 0.5*(acc+bias) -> fp32
//      4 = qkv special: cols<1024 -> 0.125*(acc+bias)->outB (q, pre-scaled);
//          cols in [1024,2048) -> (acc+bias)->outB (k);
//          cols >= 2048 -> V written TRANSPOSED to vtp[(bh*64+hd)][t].
// ---------------------------------------------------------------------------
template<int EPI>
__global__ __launch_bounds__(256)
void gemm_k(const bf16* __restrict__ A, const bf16* __restrict__ WT,
            const float* __restrict__ bias, const float* __restrict__ res,
            float* __restrict__ outF, bf16* __restrict__ outB,
            bf16* __restrict__ vtp, int N, int K)
{
    __shared__ __align__(16) bf16 As[2][128 * 32];
    __shared__ __align__(16) bf16 Bs[2][128 * 32];
    const int tid  = threadIdx.x;
    const int wave = tid >> 6;
    const int lane = tid & 63;
    const int quad = lane >> 4;
    const int lr   = lane & 15;
    const int bm = blockIdx.x * 128;
    const int bn = blockIdx.y * 128;
    const int wm = (wave & 1) * 64;
    const int wn = (wave >> 1) * 64;

    const int crow = lane >> 2;          // 0..15
    const int ccol = (lane & 3) << 3;    // 0,8,16,24

    auto stage = [&](int k0, int buf) {
#pragma unroll
        for (int t = 0; t < 2; t++) {
            const int c = wave * 2 + t;            // chunk 0..7 (16 rows each)
            async16(&A[(size_t)(bm + c * 16 + crow) * K + k0 + ccol], &As[buf][c * 512]);
            async16(&WT[(size_t)(bn + c * 16 + crow) * K + k0 + ccol], &Bs[buf][c * 512]);
        }
    };

    f32x4 acc[4][4];
#pragma unroll
    for (int mi = 0; mi < 4; mi++)
#pragma unroll
        for (int ni = 0; ni < 4; ni++)
#pragma unroll
            for (int r = 0; r < 4; r++) acc[mi][ni][r] = 0.f;

    stage(0, 0);
    __syncthreads();
    const int nk = K >> 5;
    for (int ki = 0; ki < nk; ki++) {
        const int cur = ki & 1;
        if (ki + 1 < nk) stage((ki + 1) << 5, cur ^ 1);

        bf16x8 af[4], bfr[4];
#pragma unroll
        for (int mi = 0; mi < 4; mi++)
            af[mi] = *(const bf16x8*)(&As[cur][(wm + mi * 16 + lr) * 32 + quad * 8]);
#pragma unroll
        for (int ni = 0; ni < 4; ni++)
            bfr[ni] = *(const bf16x8*)(&Bs[cur][(wn + ni * 16 + lr) * 32 + quad * 8]);
#pragma unroll
        for (int mi = 0; mi < 4; mi++)
#pragma unroll
            for (int ni = 0; ni < 4; ni++)
                acc[mi][ni] = __builtin_amdgcn_mfma_f32_16x16x32_bf16(
                    af[mi], bfr[ni], acc[mi][ni], 0, 0, 0);
        __syncthreads();
    }

    // epilogue — C/D layout: col = lane&15, row = quad*4 + reg  [m89-verified]
#pragma unroll
    for (int mi = 0; mi < 4; mi++) {
#pragma unroll
        for (int ni = 0; ni < 4; ni++) {
            int col = bn + wn + ni * 16 + lr;
            float bv = bias[col];
            if (EPI == 4 && col >= 2048) {
                // V -> transposed vt[(bh*64+hd)][t], packed 4x bf16 (8B)
                int vcol = col - 2048;
                int hh = vcol >> 6, hd = vcol & 63;
                int rowbase = bm + wm + mi * 16 + quad * 4;
                int bq = rowbase >> 10, t0 = rowbase & 1023;
                bf16x4 tmp;
#pragma unroll
                for (int r = 0; r < 4; r++) tmp[r] = (bf16)(acc[mi][ni][r] + bv);
                *(bf16x4*)(&vtp[((size_t)((bq * 16 + hh) * 64 + hd)) * T_ + t0]) = tmp;
            } else {
#pragma unroll
                for (int r = 0; r < 4; r++) {
                    int row = bm + wm + mi * 16 + quad * 4 + r;
                    size_t idx = (size_t)row * N + col;
                    float v = acc[mi][ni][r] + bv;
                    if (EPI == 0)      outB[idx] = (bf16)gelu_f(v);
                    else if (EPI == 1) outB[idx] = (bf16)v;
                    else if (EPI == 2) outF[idx] = v + res[idx];
                    else if (EPI == 3) outF[idx] = res[idx] + 0.5f * v;
                    else               outB[idx] = (bf16)(col < 1024 ? v * 0.125f : v);
                }
            }
        }
    }
}

// ---------------------------------------------------------------------------
// bf16 MFMA GEMM (BM=64, BN=128): N=1024 shapes (grid 128x8 = 4 blocks/CU).
// Same BK=32 double-buffered pipeline.
// ---------------------------------------------------------------------------
template<int EPI>
__global__ __launch_bounds__(256)
void gemm64_k(const bf16* __restrict__ A, const bf16* __restrict__ WT,
              const float* __restrict__ bias, const float* __restrict__ res,
              float* __restrict__ outF, bf16* __restrict__ outB,
              int N, int K)
{
    __shared__ __align__(16) bf16 As[2][64 * 32];
    __shared__ __align__(16) bf16 Bs[2][128 * 32];
    const int tid  = threadIdx.x;
    const int wave = tid >> 6;
    const int lane = tid & 63;
    const int quad = lane >> 4;
    const int lr   = lane & 15;
    const int bm = blockIdx.x * 64;
    const int bn = blockIdx.y * 128;
    const int wm = (wave & 1) * 32;
    const int wn = (wave >> 1) * 64;

    const int crow = lane >> 2;
    const int ccol = (lane & 3) << 3;

    auto stage = [&](int k0, int buf) {
        async16(&A[(size_t)(bm + wave * 16 + crow) * K + k0 + ccol], &As[buf][wave * 512]);
#pragma unroll
        for (int t = 0; t < 2; t++) {
            const int c = wave * 2 + t;
            async16(&WT[(size_t)(bn + c * 16 + crow) * K + k0 + ccol], &Bs[buf][c * 512]);
        }
    };

    f32x4 acc[2][4];
#pragma unroll
    for (int mi = 0; mi < 2; mi++)
#pragma unroll
        for (int ni = 0; ni < 4; ni++)
#pragma unroll
            for (int r = 0; r < 4; r++) acc[mi][ni][r] = 0.f;

    stage(0, 0);
    __syncthreads();
    const int nk = K >> 5;
    for (int ki = 0; ki < nk; ki++) {
        const int cur = ki & 1;
        if (ki + 1 < nk) stage((ki + 1) << 5, cur ^ 1);

        bf16x8 af[2], bfr[4];
#pragma unroll
        for (int mi = 0; mi < 2; mi++)
            af[mi] = *(const bf16x8*)(&As[cur][(wm + mi * 16 + lr) * 32 + quad * 8]);
#pragma unroll
        for (int ni = 0; ni < 4; ni++)
            bfr[ni] = *(const bf16x8*)(&Bs[cur][(wn + ni * 16 + lr) * 32 + quad * 8]);
#pragma unroll
        for (int mi = 0; mi < 2; mi++)
#pragma unroll
            for (int ni = 0; ni < 4; ni++)
                acc[mi][ni] = __builtin_amdgcn_mfma_f32_16x16x32_bf16(
                    af[mi], bfr[ni], acc[mi][ni], 0, 0, 0);
        __syncthreads();
    }

#pragma unroll
    for (int mi = 0; mi < 2; mi++) {
#pragma unroll
        for (int ni = 0; ni < 4; ni++) {
            int col = bn + wn + ni * 16 + lr;
            float bv = bias[col];
#pragma unroll
            for (int r = 0; r < 4; r++) {
                int row = bm + wm + mi * 16 + quad * 4 + r;
                size_t idx = (size_t)row * N + col;
                float v = acc[mi][ni][r] + bv;
                if (EPI == 0)      outB[idx] = (bf16)gelu_f(v);
                else if (EPI == 1) outB[idx] = (bf16)v;
                else if (EPI == 2) outF[idx] = v + res[idx];
                else               outF[idx] = res[idx] + 0.5f * v;
            }
        }
    }
}

// ---------------------------------------------------------------------------
// Flash attention: grid (8 q-blocks of 128 rows, B*NH), LPT order (longest
// blocks first: B0 = 7 - blockIdx.x). 4 waves; wave owns two 16-row q
// stripes. Cooperative K/V staging via global_load_lds. No-max softmax
// (|s| bounded; Q pre-scaled by 1/8 in qkv epilogue), deferred l-reduction.
// qkv: row-major [b*T+t][3072], k at +1024. vt: [bh*64+hd][t].
// ---------------------------------------------------------------------------
__global__ __launch_bounds__(256)
void attn_k(const bf16* __restrict__ qkv, const bf16* __restrict__ vt,
            bf16* __restrict__ o)
{
    const int B0 = 7 - blockIdx.x;      // LPT: longest (B0=7) dispatched first
    const int bh = blockIdx.y;          // b*16 + h
    const int b = bh >> 4, h = bh & 15;
    const int tid  = threadIdx.x;
    const int wave = tid >> 6, lane = tid & 63;
    const int quad = lane >> 4, lr = lane & 15;

    __shared__ __align__(16) bf16 Ks[2][64 * 32];   // [half][s-row][32 hd]
    __shared__ __align__(16) bf16 Vs[2][64 * 32];   // [half][hd-row][32 s]
    __shared__ __align__(16) bf16 Ps[4][16 * 72];   // per-wave P stripe [q][s]

    const int crow = lane >> 2;          // 0..15
    const int ccol = (lane & 3) << 3;    // 0,8,16,24

    const int qa = B0 * 128 + wave * 16;         // stripe a base q row
    const int qb = qa + 64;                      // stripe b base q row

    // Q fragments direct from global (already scaled by 1/8)
    bf16x8 qfa[2], qfb[2];
    {
        const size_t ra = ((size_t)(b * T_ + qa + lr)) * 3072 + h * 64;
        const size_t rb = ((size_t)(b * T_ + qb + lr)) * 3072 + h * 64;
        qfa[0] = *(const bf16x8*)(&qkv[ra + quad * 8]);
        qfa[1] = *(const bf16x8*)(&qkv[ra + 32 + quad * 8]);
        qfb[0] = *(const bf16x8*)(&qkv[rb + quad * 8]);
        qfb[1] = *(const bf16x8*)(&qkv[rb + 32 + quad * 8]);
    }

    f32x4 oa[4], ob[4];
    float la[4], lb[4];
#pragma unroll
    for (int ni = 0; ni < 4; ni++)
#pragma unroll
        for (int r = 0; r < 4; r++) { oa[ni][r] = 0.f; ob[ni][r] = 0.f; }
#pragma unroll
    for (int r = 0; r < 4; r++) { la[r] = 0.f; lb[r] = 0.f; }

    const size_t kbase = (size_t)b * T_ * 3072 + 1024 + h * 64;
    const size_t vbase = (size_t)bh * 64 * T_;

    auto stripe = [&](const bf16x8 (&qf)[2], f32x4 (&oacc)[4], float (&lsum)[4],
                      int q0, int kcol0, bool diag) {
        bf16x8 kf0[4], kf1[4];
#pragma unroll
        for (int ni = 0; ni < 4; ni++) {
            kf0[ni] = *(const bf16x8*)(&Ks[0][(ni * 16 + lr) * 32 + quad * 8]);
            kf1[ni] = *(const bf16x8*)(&Ks[1][(ni * 16 + lr) * 32 + quad * 8]);
        }
        f32x4 sv[4];
#pragma unroll
        for (int ni = 0; ni < 4; ni++) {
            f32x4 t;
#pragma unroll
            for (int r = 0; r < 4; r++) t[r] = 0.f;
            t = __builtin_amdgcn_mfma_f32_16x16x32_bf16(qf[0], kf0[ni], t, 0, 0, 0);
            t = __builtin_amdgcn_mfma_f32_16x16x32_bf16(qf[1], kf1[ni], t, 0, 0, 0);
            sv[ni] = t;
        }
        if (diag) {
#pragma unroll
            for (int ni = 0; ni < 4; ni++)
#pragma unroll
                for (int r = 0; r < 4; r++)
                    if (kcol0 + ni * 16 + lr > q0 + quad * 4 + r)
                        sv[ni][r] = -INFINITY;
        }
#pragma unroll
        for (int ni = 0; ni < 4; ni++)
#pragma unroll
            for (int r = 0; r < 4; r++) {
                float p = __expf(sv[ni][r]);   // no-max softmax: |s| bounded
                lsum[r] += p;
                Ps[wave][(quad * 4 + r) * 72 + ni * 16 + lr] = (bf16)p;
            }
        bf16x8 pf0 = *(const bf16x8*)(&Ps[wave][lr * 72 + quad * 8]);
        bf16x8 pf1 = *(const bf16x8*)(&Ps[wave][lr * 72 + 32 + quad * 8]);
#pragma unroll
        for (int ni = 0; ni < 4; ni++) {
            bf16x8 vf0 = *(const bf16x8*)(&Vs[0][(ni * 16 + lr) * 32 + quad * 8]);
            bf16x8 vf1 = *(const bf16x8*)(&Vs[1][(ni * 16 + lr) * 32 + quad * 8]);
            oacc[ni] = __builtin_amdgcn_mfma_f32_16x16x32_bf16(pf0, vf0, oacc[ni], 0, 0, 0);
            oacc[ni] = __builtin_amdgcn_mfma_f32_16x16x32_bf16(pf1, vf1, oacc[ni], 0, 0, 0);
        }
    };

    const int ktmax = 2 * B0 + 1;
    for (int kt = 0; kt <= ktmax; kt++) {
        __syncthreads();
#pragma unroll
        for (int half = 0; half < 2; half++) {
            async16(&qkv[kbase + (size_t)(kt * 64 + wave * 16 + crow) * 3072 + half * 32 + ccol],
                    &Ks[half][wave * 512]);
            async16(&vt[vbase + (size_t)(wave * 16 + crow) * T_ + kt * 64 + half * 32 + ccol],
                    &Vs[half][wave * 512]);
        }
        __syncthreads();
        if (kt <= 2 * B0)
            stripe(qfa, oa, la, qa, kt * 64, kt == 2 * B0);
        stripe(qfb, ob, lb, qb, kt * 64, kt == ktmax);
    }

    // final l reduction across the 16 lanes of each row group
#pragma unroll
    for (int off = 1; off < 16; off <<= 1)
#pragma unroll
        for (int r = 0; r < 4; r++) {
            la[r] += __shfl_xor(la[r], off);
            lb[r] += __shfl_xor(lb[r], off);
        }

#pragma unroll
    for (int r = 0; r < 4; r++) {
        float inva = 1.0f / la[r], invb = 1.0f / lb[r];
        int ga = qa + quad * 4 + r, gb = qb + quad * 4 + r;
#pragma unroll
        for (int ni = 0; ni < 4; ni++) {
            o[((size_t)(b * T_ + ga)) * H_ + h * 64 + ni * 16 + lr] = (bf16)(oa[ni][r] * inva);
            o[((size_t)(b * T_ + gb)) * H_ + h * 64 + ni * 16 + lr] = (bf16)(ob[ni][r] * invb);
        }
    }
}

// ---------------------------------------------------------------------------
extern "C" void kernel_launch(void* const* d_in, const int* in_sizes, int n_in,
                              void* d_out, int out_size, void* d_ws, size_t ws_size,
                              hipStream_t stream)
{
    const float* x_in  = (const float*)d_in[0];
    const float* ln1_g = (const float*)d_in[1];
    const float* ln1_b = (const float*)d_in[2];
    const float* f1w1  = (const float*)d_in[3];
    const float* f1b1  = (const float*)d_in[4];
    const float* f1w2  = (const float*)d_in[5];
    const float* f1b2  = (const float*)d_in[6];
    const float* an_g  = (const float*)d_in[7];
    const float* an_b  = (const float*)d_in[8];
    const float* qkv_w = (const float*)d_in[9];
    const float* qkv_b = (const float*)d_in[10];
    const float* out_w = (const float*)d_in[11];
    const float* out_b = (const float*)d_in[12];
    const float* cn_g  = (const float*)d_in[13];
    const float* cn_b  = (const float*)d_in[14];
    const float* dw_k  = (const float*)d_in[15];
    const float* dw_b  = (const float*)d_in[16];
    const float* pw_w  = (const float*)d_in[17];
    const float* pw_b  = (const float*)d_in[18];
    const float* ln2_g = (const float*)d_in[19];
    const float* ln2_b = (const float*)d_in[20];
    const float* f2w1  = (const float*)d_in[21];
    const float* f2b1  = (const float*)d_in[22];
    const float* f2w2  = (const float*)d_in[23];
    const float* f2b2  = (const float*)d_in[24];
    float* outp = (float*)d_out;

    char* ws = (char*)d_ws;
    size_t off = 0;
    auto alloc = [&](size_t bytes) {
        char* p = ws + off;
        off += (bytes + 255) & ~(size_t)255;
        return p;
    };
    bf16* w1T_1 = (bf16*)alloc(2048ULL * 1024 * 2);
    bf16* w2T_1 = (bf16*)alloc(1024ULL * 2048 * 2);
    bf16* qkvT  = (bf16*)alloc(3072ULL * 1024 * 2);
    bf16* outT  = (bf16*)alloc(1024ULL * 1024 * 2);
    bf16* pwB   = (bf16*)alloc(1024ULL * 1024 * 2);
    bf16* w1T_2 = (bf16*)alloc(2048ULL * 1024 * 2);
    bf16* w2T_2 = (bf16*)alloc(1024ULL * 2048 * 2);
    bf16* bufa  = (bf16*)alloc((size_t)MTOK * 1024 * 2);   // LN outs / attn out
    bf16* gbuf  = (bf16*)alloc((size_t)MTOK * 1024 * 2);   // conv-gelu out / vt alias
    bf16* hid   = (bf16*)alloc((size_t)MTOK * 3072 * 2);   // ffn hidden / qkv
    float* xw   = (float*)alloc((size_t)MTOK * 1024 * 4);  // running residual x
    bf16* vt    = gbuf;   // time-disjoint alias: vt live only during attention

    // ---- weight prep: ONE kernel (6 transposes + 1 cast) ----
    PrepTab tab;
    tab.in[0] = f1w1;  tab.out[0] = w1T_1; tab.kd[0] = 1024; tab.nd[0] = 2048; tab.mode[0] = 0;
    tab.in[1] = f1w2;  tab.out[1] = w2T_1; tab.kd[1] = 2048; tab.nd[1] = 1024; tab.mode[1] = 0;
    tab.in[2] = qkv_w; tab.out[2] = qkvT;  tab.kd[2] = 1024; tab.nd[2] = 3072; tab.mode[2] = 0;
    tab.in[3] = out_w; tab.out[3] = outT;  tab.kd[3] = 1024; tab.nd[3] = 1024; tab.mode[3] = 0;
    tab.in[4] = f2w1;  tab.out[4] = w1T_2; tab.kd[4] = 1024; tab.nd[4] = 2048; tab.mode[4] = 0;
    tab.in[5] = f2w2;  tab.out[5] = w2T_2; tab.kd[5] = 2048; tab.nd[5] = 1024; tab.mode[5] = 0;
    tab.in[6] = pw_w;  tab.out[6] = pwB;   tab.kd[6] = 1024; tab.nd[6] = 1024; tab.mode[6] = 1;
    tab.bx0[0] = 0;
    for (int j = 0; j < 7; j++) {
        int blocks = tab.mode[j] ? (tab.kd[j] * tab.nd[j] / 1024)
                                 : (tab.kd[j] / 32) * (tab.nd[j] / 32);
        tab.bx0[j + 1] = tab.bx0[j] + blocks;
    }
    prep_k<<<tab.bx0[7], 256, 0, stream>>>(tab);

    // ---- FFN1 (x += 0.5 * ffn(ln1(x))) ----
    ln_k<<<MTOK, 256, 0, stream>>>(x_in, ln1_g, ln1_b, bufa);
    gemm_k<0><<<dim3(64, 16), 256, 0, stream>>>(bufa, w1T_1, f1b1, nullptr, nullptr, hid, nullptr, 2048, 1024);
    gemm64_k<3><<<dim3(128, 8), 256, 0, stream>>>(hid, w2T_1, f1b2, x_in, xw, nullptr, 1024, 2048);

    // ---- attention (qkv GEMM writes q (scaled), k to hid; V transposed to vt) ----
    ln_k<<<MTOK, 256, 0, stream>>>(xw, an_g, an_b, bufa);
    gemm_k<4><<<dim3(64, 24), 256, 0, stream>>>(bufa, qkvT, qkv_b, nullptr, nullptr, hid, vt, 3072, 1024);
    attn_k<<<dim3(8, 128), 256, 0, stream>>>(hid, vt, bufa);
    gemm64_k<2><<<dim3(128, 8), 256, 0, stream>>>(bufa, outT, out_b, xw, xw, nullptr, 1024, 1024);

    // ---- conv module ----
    ln_k<<<MTOK, 256, 0, stream>>>(xw, cn_g, cn_b, bufa);
    dwconv_k<<<MTOK * 1024 / 256, 256, 0, stream>>>(bufa, dw_k, dw_b, gbuf);
    gemm64_k<2><<<dim3(128, 8), 256, 0, stream>>>(gbuf, pwB, pw_b, xw, xw, nullptr, 1024, 1024);

    // ---- FFN2 ----
    ln_k<<<MTOK, 256, 0, stream>>>(xw, ln2_g, ln2_b, bufa);
    gemm_k<0><<<dim3(64, 16), 256, 0, stream>>>(bufa, w1T_2, f2b1, nullptr, nullptr, hid, nullptr, 2048, 1024);
    gemm64_k<3><<<dim3(128, 8), 256, 0, stream>>>(hid, w2T_2, f2b2, xw, outp, nullptr, 1024, 2048);
}